// Round 2
// baseline (99.612 us; speedup 1.0000x reference)
//
#include <hip/hip_runtime.h>

#define Bn 8
#define Nn 1024
#define Fn 512
#define Rn 32

#define T1   512            // threads in GEMM kernels
#define ROWS 32             // rows of x per block
#define GR   (T1 / Rn)      // 16 groups (each group = 32 lanes owning all r)
#define RPT  (ROWS / GR)    // 2 rows per thread

// ---------------------------------------------------------------------------
// k1: fused x@{W1,W2,Wg}. Stores z1+bias to ws, atomically accumulates
//     gsum[b,r] = sum_n g[b,n,r], z2gsum[b,r] = sum_n z2[b,n,r]*g[b,n,r].
// ---------------------------------------------------------------------------
__global__ __launch_bounds__(T1)
void k1(const float* __restrict__ x, const float* __restrict__ W1,
        const float* __restrict__ W2, const float* __restrict__ Wg,
        const float* __restrict__ bias, float* __restrict__ z1out,
        float* __restrict__ gsum, float* __restrict__ z2gsum)
{
    __shared__ float xs[ROWS * Fn];          // 64 KB
    const int t = threadIdx.x;
    const int row0 = blockIdx.x * ROWS;      // global row (b*1024+n)
    const int bb = row0 / Nn;                // 32 | 1024 -> whole block same b

    // stage x rows (coalesced float4)
    {
        float4* s4 = (float4*)xs;
        const float4* g4 = (const float4*)(x + (size_t)row0 * Fn);
        #pragma unroll
        for (int i = 0; i < (ROWS * Fn / 4) / T1; ++i)
            s4[t + i * T1] = g4[t + i * T1];
    }
    __syncthreads();

    const int r = t & (Rn - 1);
    const int g = t >> 5;                    // 16 groups, 2 rows each

    float a1[RPT] = {0.f, 0.f};
    float a2[RPT] = {0.f, 0.f};
    float ag[RPT] = {0.f, 0.f};
    const float4* xr0 = (const float4*)(xs + (g * RPT + 0) * Fn);
    const float4* xr1 = (const float4*)(xs + (g * RPT + 1) * Fn);
    const float* w1p = W1 + r;
    const float* w2p = W2 + r;
    const float* wgp = Wg + r;

    #pragma unroll 4
    for (int f4 = 0; f4 < Fn / 4; ++f4) {
        float4 v0 = xr0[f4];
        float4 v1 = xr1[f4];
        float xv[RPT][4] = {{v0.x, v0.y, v0.z, v0.w},
                            {v1.x, v1.y, v1.z, v1.w}};
        #pragma unroll
        for (int k = 0; k < 4; ++k) {
            const int f = f4 * 4 + k;
            const float w1 = w1p[f * Rn];
            const float w2 = w2p[f * Rn];
            const float wg = wgp[f * Rn];
            #pragma unroll
            for (int i = 0; i < RPT; ++i) {
                a1[i] = fmaf(xv[i][k], w1, a1[i]);
                a2[i] = fmaf(xv[i][k], w2, a2[i]);
                ag[i] = fmaf(xv[i][k], wg, ag[i]);
            }
        }
    }

    // store z1 (+bias) — coalesced 128B per 32-lane group
    const float bv = bias[r];
    if (z1out) {
        #pragma unroll
        for (int i = 0; i < RPT; ++i)
            z1out[(size_t)(row0 + g * RPT + i) * Rn + r] = a1[i] + bv;
    }

    // per-thread partials over its rows
    float pg = 0.f, pz = 0.f;
    #pragma unroll
    for (int i = 0; i < RPT; ++i) { pg += ag[i]; pz += a2[i] * ag[i]; }

    // block reduce across the 16 groups (reuse xs)
    __syncthreads();                         // everyone done reading xs
    xs[g * Rn + r]            = pg;
    xs[GR * Rn + g * Rn + r]  = pz;
    __syncthreads();
    if (t < Rn) {
        float sg = 0.f, sz = 0.f;
        #pragma unroll
        for (int gg = 0; gg < GR; ++gg) {
            sg += xs[gg * Rn + t];
            sz += xs[GR * Rn + gg * Rn + t];
        }
        atomicAdd(&gsum[bb * Rn + t], sg);
        atomicAdd(&z2gsum[bb * Rn + t], sz);
    }
}

// ---------------------------------------------------------------------------
// k2: out = z1 * gsum[b,:] + z2gsum[b,:]   (trivial broadcast epilogue)
// ---------------------------------------------------------------------------
__global__ __launch_bounds__(256)
void k2(const float4* __restrict__ z1, const float* __restrict__ gsum,
        const float* __restrict__ z2gsum, float4* __restrict__ out)
{
    const int i = blockIdx.x * 256 + threadIdx.x;    // 65536 float4s
    const int e = i << 2;
    const int bb = e >> 15;                          // / (1024*32)
    const int rb = e & (Rn - 1);                     // r of first component
    const float4 z  = z1[i];
    const float4 gs = *(const float4*)(gsum   + bb * Rn + rb);
    const float4 zg = *(const float4*)(z2gsum + bb * Rn + rb);
    float4 o;
    o.x = fmaf(z.x, gs.x, zg.x);
    o.y = fmaf(z.y, gs.y, zg.y);
    o.z = fmaf(z.z, gs.z, zg.z);
    o.w = fmaf(z.w, gs.w, zg.w);
    out[i] = o;
}

// ---------------------------------------------------------------------------
// k2b: fallback if ws too small for z1 — recompute z1 = x@W1+b and finish.
// ---------------------------------------------------------------------------
__global__ __launch_bounds__(T1)
void k2b(const float* __restrict__ x, const float* __restrict__ W1,
         const float* __restrict__ bias, const float* __restrict__ gsum,
         const float* __restrict__ z2gsum, float* __restrict__ out)
{
    __shared__ float xs[ROWS * Fn];
    const int t = threadIdx.x;
    const int row0 = blockIdx.x * ROWS;
    const int bb = row0 / Nn;

    {
        float4* s4 = (float4*)xs;
        const float4* g4 = (const float4*)(x + (size_t)row0 * Fn);
        #pragma unroll
        for (int i = 0; i < (ROWS * Fn / 4) / T1; ++i)
            s4[t + i * T1] = g4[t + i * T1];
    }
    __syncthreads();

    const int r = t & (Rn - 1);
    const int g = t >> 5;
    float a1[RPT] = {0.f, 0.f};
    const float4* xr0 = (const float4*)(xs + (g * RPT + 0) * Fn);
    const float4* xr1 = (const float4*)(xs + (g * RPT + 1) * Fn);
    const float* w1p = W1 + r;

    #pragma unroll 4
    for (int f4 = 0; f4 < Fn / 4; ++f4) {
        float4 v0 = xr0[f4];
        float4 v1 = xr1[f4];
        float xv[RPT][4] = {{v0.x, v0.y, v0.z, v0.w},
                            {v1.x, v1.y, v1.z, v1.w}};
        #pragma unroll
        for (int k = 0; k < 4; ++k) {
            const float w1 = w1p[(f4 * 4 + k) * Rn];
            #pragma unroll
            for (int i = 0; i < RPT; ++i)
                a1[i] = fmaf(xv[i][k], w1, a1[i]);
        }
    }

    const float gv0 = gsum[bb * Rn + r];
    const float zg0 = z2gsum[bb * Rn + r];
    const float bv  = bias[r];
    #pragma unroll
    for (int i = 0; i < RPT; ++i) {
        const int row = row0 + g * RPT + i;
        out[(size_t)row * Rn + r] = fmaf(a1[i] + bv, gv0, zg0);
    }
}

// ---------------------------------------------------------------------------
extern "C" void kernel_launch(void* const* d_in, const int* in_sizes, int n_in,
                              void* d_out, int out_size, void* d_ws, size_t ws_size,
                              hipStream_t stream)
{
    const float* x    = (const float*)d_in[0];
    const float* W1   = (const float*)d_in[1];
    const float* W2   = (const float*)d_in[2];
    const float* Wg   = (const float*)d_in[3];
    const float* bias = (const float*)d_in[4];
    float* out = (float*)d_out;

    const size_t z1_bytes  = (size_t)Bn * Nn * Rn * sizeof(float);  // 1 MB
    const size_t sum_bytes = (size_t)2 * Bn * Rn * sizeof(float);   // 2 KB
    const bool big = ws_size >= z1_bytes + sum_bytes;

    float* z1     = big ? (float*)d_ws : nullptr;
    float* gsum   = big ? (float*)((char*)d_ws + z1_bytes) : (float*)d_ws;
    float* z2gsum = gsum + Bn * Rn;

    hipMemsetAsync(gsum, 0, sum_bytes, stream);     // ws is re-poisoned to 0xAA

    k1<<<dim3((Bn * Nn) / ROWS), dim3(T1), 0, stream>>>(
        x, W1, W2, Wg, bias, z1, gsum, z2gsum);

    if (big) {
        k2<<<dim3((Bn * Nn * Rn / 4) / 256), dim3(256), 0, stream>>>(
            (const float4*)z1, gsum, z2gsum, (float4*)out);
    } else {
        k2b<<<dim3((Bn * Nn) / ROWS), dim3(T1), 0, stream>>>(
            x, W1, bias, gsum, z2gsum, out);
    }
}

// Round 5
// 83.380 us; speedup vs baseline: 1.1947x; 1.1947x over previous
//
#include <hip/hip_runtime.h>
#include <hip/hip_bf16.h>

#define Bn 8
#define Nn 1024
#define Fn 512
#define Rn 32

typedef __attribute__((ext_vector_type(8))) short bf16x8;
typedef __attribute__((ext_vector_type(4))) float f32x4;

// ---------------------------------------------------------------------------
// kW: W[f][r] f32 -> Wt[m][r][f] bf16 (transpose so B-fragments are 16B rows)
// 24 blocks x 256 thr; LDS transpose, +1-padded against bank conflicts.
// ---------------------------------------------------------------------------
__global__ __launch_bounds__(256)
void kW(const float* __restrict__ W1, const float* __restrict__ W2,
        const float* __restrict__ Wg, short* __restrict__ Wt)
{
    __shared__ float xs[64 * 33];
    const int m  = blockIdx.x >> 3;         // 0..2
    const int f0 = (blockIdx.x & 7) * 64;   // 0..448
    const float* W = (m == 0) ? W1 : (m == 1) ? W2 : Wg;
    const int t = threadIdx.x;

    #pragma unroll
    for (int i = 0; i < 8; ++i) {           // coalesced read of 64f x 32r tile
        int idx = t + i * 256;              // 0..2047
        int fi = idx >> 5, r = idx & 31;
        xs[fi * 33 + r] = W[(size_t)(f0 + fi) * Rn + r];
    }
    __syncthreads();

    short* out = Wt + (size_t)m * (Rn * Fn);
    #pragma unroll
    for (int i = 0; i < 8; ++i) {           // coalesced bf16 write of transpose
        int j = t + i * 256;                // j = r*64 + fi
        int r = j >> 6, fi = j & 63;
        __hip_bfloat16 h = __float2bfloat16(xs[fi * 33 + r]);
        out[(size_t)r * Fn + f0 + fi] = *reinterpret_cast<short*>(&h);
    }
}

// ---------------------------------------------------------------------------
// k1: one wave per 16-row tile. A-frag from global f32 (cvt->bf16), shared by
// 3 GEMMs; B-frags = contiguous bf16x8 from Wt. z1(+bias) -> ws; gsum/z2gsum
// shuffle-reduced + atomicAdd.
// MFMA 16x16x32 bf16: A row=lane&15, k=8*(lane>>4)+i ; B col=lane&15, same k.
// C/D (m89-verified): col=lane&15, row=(lane>>4)*4+reg.
// ---------------------------------------------------------------------------
__global__ __launch_bounds__(64)
void k1(const float* __restrict__ x, const short* __restrict__ Wt,
        const float* __restrict__ bias, float* __restrict__ z1,
        float* __restrict__ gsum, float* __restrict__ z2gsum)
{
    const int l    = threadIdx.x;
    const int row0 = blockIdx.x * 16;       // 512 blocks cover 8192 rows
    const int bb   = row0 >> 10;            // batch index
    const int lr   = l & 15;                // A: row-in-tile / B: column
    const int lk   = l >> 4;                // k-group 0..3

    const float* xrow = x + (size_t)(row0 + lr) * Fn + 8 * lk;
    const short* w0   = Wt + 8 * lk;

    f32x4 acc1[2] = {}, acc2[2] = {}, accg[2] = {};

    #pragma unroll
    for (int kk = 0; kk < 16; ++kk) {
        // A fragment: 8 consecutive f32 along K -> bf16x8
        float4 v0 = *(const float4*)(xrow + kk * 32);
        float4 v1 = *(const float4*)(xrow + kk * 32 + 4);
        float f[8] = {v0.x, v0.y, v0.z, v0.w, v1.x, v1.y, v1.z, v1.w};
        bf16x8 a;
        #pragma unroll
        for (int i = 0; i < 8; ++i) {
            __hip_bfloat16 h = __float2bfloat16(f[i]);
            a[i] = *reinterpret_cast<short*>(&h);
        }
        #pragma unroll
        for (int h = 0; h < 2; ++h) {       // two 16-col halves of R=32
            const short* wp = w0 + (size_t)(h * 16 + lr) * Fn + kk * 32;
            bf16x8 b1 = *(const bf16x8*)(wp);
            bf16x8 b2 = *(const bf16x8*)(wp + 16384);   // W2 plane
            bf16x8 bg = *(const bf16x8*)(wp + 32768);   // Wg plane
            acc1[h] = __builtin_amdgcn_mfma_f32_16x16x32_bf16(a, b1, acc1[h], 0, 0, 0);
            acc2[h] = __builtin_amdgcn_mfma_f32_16x16x32_bf16(a, b2, acc2[h], 0, 0, 0);
            accg[h] = __builtin_amdgcn_mfma_f32_16x16x32_bf16(a, bg, accg[h], 0, 0, 0);
        }
    }

    // z1 (+bias) store: row = row0 + lk*4 + reg, col = h*16 + lr
    const float bv[2] = {bias[lr], bias[16 + lr]};
    #pragma unroll
    for (int h = 0; h < 2; ++h) {
        #pragma unroll
        for (int reg = 0; reg < 4; ++reg) {
            int row = row0 + lk * 4 + reg;
            z1[(size_t)row * Rn + h * 16 + lr] = acc1[h][reg] + bv[h];
        }
    }

    // per-lane partials (4 rows each) then reduce over lk (lanes xor 16,32)
    float sg[2] = {0.f, 0.f}, sz[2] = {0.f, 0.f};
    #pragma unroll
    for (int h = 0; h < 2; ++h)
        #pragma unroll
        for (int reg = 0; reg < 4; ++reg) {
            float gv = accg[h][reg];
            sg[h] += gv;
            sz[h] += acc2[h][reg] * gv;
        }
    #pragma unroll
    for (int h = 0; h < 2; ++h) {
        sg[h] += __shfl_xor(sg[h], 16); sg[h] += __shfl_xor(sg[h], 32);
        sz[h] += __shfl_xor(sz[h], 16); sz[h] += __shfl_xor(sz[h], 32);
    }
    if (l < 16) {
        atomicAdd(&gsum[bb * Rn + lr],        sg[0]);
        atomicAdd(&gsum[bb * Rn + 16 + lr],   sg[1]);
        atomicAdd(&z2gsum[bb * Rn + lr],      sz[0]);
        atomicAdd(&z2gsum[bb * Rn + 16 + lr], sz[1]);
    }
}

// ---------------------------------------------------------------------------
// k2: out = z1 * gsum[b,:] + z2gsum[b,:]   (z1 already includes bias)
// ---------------------------------------------------------------------------
__global__ __launch_bounds__(256)
void k2(const float4* __restrict__ z1, const float* __restrict__ gsum,
        const float* __restrict__ z2gsum, float4* __restrict__ out)
{
    const int i = blockIdx.x * 256 + threadIdx.x;    // 65536 float4s
    const int e = i << 2;
    const int bb = e >> 15;                          // / (1024*32)
    const int rb = e & (Rn - 1);
    const float4 z  = z1[i];
    const float4 gs = *(const float4*)(gsum   + bb * Rn + rb);
    const float4 zg = *(const float4*)(z2gsum + bb * Rn + rb);
    float4 o;
    o.x = fmaf(z.x, gs.x, zg.x);
    o.y = fmaf(z.y, gs.y, zg.y);
    o.z = fmaf(z.z, gs.z, zg.z);
    o.w = fmaf(z.w, gs.w, zg.w);
    out[i] = o;
}

// ---------------------------------------------------------------------------
extern "C" void kernel_launch(void* const* d_in, const int* in_sizes, int n_in,
                              void* d_out, int out_size, void* d_ws, size_t ws_size,
                              hipStream_t stream)
{
    const float* x    = (const float*)d_in[0];
    const float* W1   = (const float*)d_in[1];
    const float* W2   = (const float*)d_in[2];
    const float* Wg   = (const float*)d_in[3];
    const float* bias = (const float*)d_in[4];
    float* out = (float*)d_out;

    // ws layout: Wt bf16 [3*32*512] (96 KB) | z1 f32 [8192*32] (1 MB) | sums
    short* Wt     = (short*)d_ws;
    float* z1     = (float*)((char*)d_ws + 3 * Rn * Fn * sizeof(short));
    float* gsum   = (float*)((char*)z1 + (size_t)Bn * Nn * Rn * sizeof(float));
    float* z2gsum = gsum + Bn * Rn;

    hipMemsetAsync(gsum, 0, 2 * Bn * Rn * sizeof(float), stream);

    kW<<<dim3(24), dim3(256), 0, stream>>>(W1, W2, Wg, Wt);

    k1<<<dim3((Bn * Nn) / 16), dim3(64), 0, stream>>>(
        x, Wt, bias, z1, gsum, z2gsum);

    k2<<<dim3((Bn * Nn * Rn / 4) / 256), dim3(256), 0, stream>>>(
        (const float4*)z1, gsum, z2gsum, (float4*)out);
}

// Round 8
// 82.083 us; speedup vs baseline: 1.2136x; 1.0158x over previous
//
#include <hip/hip_runtime.h>
#include <hip/hip_bf16.h>

#define Bn 8
#define Nn 1024
#define Fn 512
#define Rn 32

typedef __attribute__((ext_vector_type(8))) short bf16x8;
typedef __attribute__((ext_vector_type(4))) float f32x4;

// ---------------------------------------------------------------------------
// kW: W[f][r] f32 -> Wt[m][r][f] bf16 (transpose so B-fragments are 16B rows)
// ---------------------------------------------------------------------------
__global__ __launch_bounds__(256)
void kW(const float* __restrict__ W1, const float* __restrict__ W2,
        const float* __restrict__ Wg, short* __restrict__ Wt)
{
    __shared__ float xs[64 * 33];
    const int m  = blockIdx.x >> 3;         // 0..2
    const int f0 = (blockIdx.x & 7) * 64;   // 0..448
    const float* W = (m == 0) ? W1 : (m == 1) ? W2 : Wg;
    const int t = threadIdx.x;

    #pragma unroll
    for (int i = 0; i < 8; ++i) {           // coalesced read of 64f x 32r tile
        int idx = t + i * 256;
        int fi = idx >> 5, r = idx & 31;
        xs[fi * 33 + r] = W[(size_t)(f0 + fi) * Rn + r];
    }
    __syncthreads();

    short* out = Wt + (size_t)m * (Rn * Fn);
    #pragma unroll
    for (int i = 0; i < 8; ++i) {           // coalesced bf16 write of transpose
        int j = t + i * 256;                // j = r*64 + fi
        int r = j >> 6, fi = j & 63;
        __hip_bfloat16 h = __float2bfloat16(xs[fi * 33 + r]);
        out[(size_t)r * Fn + f0 + fi] = *reinterpret_cast<short*>(&h);
    }
}

// ---------------------------------------------------------------------------
// k1: 512 blocks x 256 thr (4 waves). Block owns a 16-row M-tile; wave w owns
// K-quarter [128w,128w+128) -> 4 MFMA K-steps. Partials (z1,z2,g) reduced
// across waves in LDS; z1(+bias) stored coalesced; gsum/z2gsum block-reduced
// then 2 atomics per column.
// MFMA 16x16x32 bf16: A row=lane&15, k=8*(lane>>4)+i ; B col=lane&15, same k.
// C/D (hw-verified r5): col=lane&15, row=(lane>>4)*4+reg.
// ---------------------------------------------------------------------------
__global__ __launch_bounds__(256)
void k1(const float* __restrict__ x, const short* __restrict__ Wt,
        const float* __restrict__ bias, float* __restrict__ z1,
        float* __restrict__ gsum, float* __restrict__ z2gsum)
{
    __shared__ float red[3][4][16][32];     // 24 KB: [acc][K-part][row][col]
    const int t    = threadIdx.x;
    const int l    = t & 63;
    const int w    = t >> 6;                // K-part 0..3
    const int row0 = blockIdx.x * 16;
    const int bb   = row0 >> 10;
    const int lr   = l & 15;
    const int lk   = l >> 4;

    const float* xrow = x + (size_t)(row0 + lr) * Fn + w * 128 + 8 * lk;
    const short* w0   = Wt + w * 128 + 8 * lk;

    f32x4 acc1[2] = {}, acc2[2] = {}, accg[2] = {};

    #pragma unroll
    for (int kk = 0; kk < 4; ++kk) {
        float4 v0 = *(const float4*)(xrow + kk * 32);
        float4 v1 = *(const float4*)(xrow + kk * 32 + 4);
        float f[8] = {v0.x, v0.y, v0.z, v0.w, v1.x, v1.y, v1.z, v1.w};
        bf16x8 a;
        #pragma unroll
        for (int i = 0; i < 8; ++i) {
            __hip_bfloat16 h = __float2bfloat16(f[i]);
            a[i] = *reinterpret_cast<short*>(&h);
        }
        #pragma unroll
        for (int h = 0; h < 2; ++h) {       // two 16-col halves of R=32
            const short* wp = w0 + (size_t)(h * 16 + lr) * Fn + kk * 32;
            bf16x8 b1 = *(const bf16x8*)(wp);
            bf16x8 b2 = *(const bf16x8*)(wp + 16384);   // W2 plane
            bf16x8 bg = *(const bf16x8*)(wp + 32768);   // Wg plane
            acc1[h] = __builtin_amdgcn_mfma_f32_16x16x32_bf16(a, b1, acc1[h], 0, 0, 0);
            acc2[h] = __builtin_amdgcn_mfma_f32_16x16x32_bf16(a, b2, acc2[h], 0, 0, 0);
            accg[h] = __builtin_amdgcn_mfma_f32_16x16x32_bf16(a, bg, accg[h], 0, 0, 0);
        }
    }

    // write per-wave partials: row=lk*4+reg, col=h*16+lr (4-way bank, cheap)
    #pragma unroll
    for (int h = 0; h < 2; ++h)
        #pragma unroll
        for (int reg = 0; reg < 4; ++reg) {
            const int rr = lk * 4 + reg, cc = h * 16 + lr;
            red[0][w][rr][cc] = acc1[h][reg];
            red[1][w][rr][cc] = acc2[h][reg];
            red[2][w][rr][cc] = accg[h][reg];
        }
    __syncthreads();

    // reduce over K-parts: thread t owns (row=t>>5, col=t&31) and (+8 rows)
    const int col = t & 31, r0 = t >> 5;
    float z1a = 0.f, z2a = 0.f, ga = 0.f, z1b = 0.f, z2b = 0.f, gb = 0.f;
    #pragma unroll
    for (int ww = 0; ww < 4; ++ww) {
        z1a += red[0][ww][r0][col];     z1b += red[0][ww][r0 + 8][col];
        z2a += red[1][ww][r0][col];     z2b += red[1][ww][r0 + 8][col];
        ga  += red[2][ww][r0][col];     gb  += red[2][ww][r0 + 8][col];
    }
    const float bv = bias[col];
    z1[(size_t)(row0 + r0) * Rn + col]     = z1a + bv;   // contiguous: elem==t
    z1[(size_t)(row0 + r0 + 8) * Rn + col] = z1b + bv;

    const float pg = ga + gb;
    const float pz = z2a * ga + z2b * gb;
    __syncthreads();                        // all reads of red done
    float* r2 = (float*)red;                // reuse as [2][8][32]
    r2[r0 * 32 + col]       = pg;
    r2[256 + r0 * 32 + col] = pz;
    __syncthreads();
    if (t < 32) {
        float sg = 0.f, sz = 0.f;
        #pragma unroll
        for (int i = 0; i < 8; ++i) {
            sg += r2[i * 32 + t];
            sz += r2[256 + i * 32 + t];
        }
        atomicAdd(&gsum[bb * Rn + t],   sg);
        atomicAdd(&z2gsum[bb * Rn + t], sz);
    }
}

// ---------------------------------------------------------------------------
// k2: out = z1 * gsum[b,:] + z2gsum[b,:]   (z1 already includes bias)
// ---------------------------------------------------------------------------
__global__ __launch_bounds__(256)
void k2(const float4* __restrict__ z1, const float* __restrict__ gsum,
        const float* __restrict__ z2gsum, float4* __restrict__ out)
{
    const int i = blockIdx.x * 256 + threadIdx.x;    // 65536 float4s
    const int e = i << 2;
    const int bb = e >> 15;                          // / (1024*32)
    const int rb = e & (Rn - 1);
    const float4 z  = z1[i];
    const float4 gs = *(const float4*)(gsum   + bb * Rn + rb);
    const float4 zg = *(const float4*)(z2gsum + bb * Rn + rb);
    float4 o;
    o.x = fmaf(z.x, gs.x, zg.x);
    o.y = fmaf(z.y, gs.y, zg.y);
    o.z = fmaf(z.z, gs.z, zg.z);
    o.w = fmaf(z.w, gs.w, zg.w);
    out[i] = o;
}

// ---------------------------------------------------------------------------
extern "C" void kernel_launch(void* const* d_in, const int* in_sizes, int n_in,
                              void* d_out, int out_size, void* d_ws, size_t ws_size,
                              hipStream_t stream)
{
    const float* x    = (const float*)d_in[0];
    const float* W1   = (const float*)d_in[1];
    const float* W2   = (const float*)d_in[2];
    const float* Wg   = (const float*)d_in[3];
    const float* bias = (const float*)d_in[4];
    float* out = (float*)d_out;

    // ws layout: Wt bf16 [3*32*512] (96 KB) | z1 f32 [8192*32] (1 MB) | sums
    short* Wt     = (short*)d_ws;
    float* z1     = (float*)((char*)d_ws + 3 * Rn * Fn * sizeof(short));
    float* gsum   = (float*)((char*)z1 + (size_t)Bn * Nn * Rn * sizeof(float));
    float* z2gsum = gsum + Bn * Rn;

    hipMemsetAsync(gsum, 0, 2 * Bn * Rn * sizeof(float), stream);

    kW<<<dim3(24), dim3(256), 0, stream>>>(W1, W2, Wg, Wt);

    k1<<<dim3((Bn * Nn) / 16), dim3(256), 0, stream>>>(
        x, Wt, bias, z1, gsum, z2gsum);

    k2<<<dim3((Bn * Nn * Rn / 4) / 256), dim3(256), 0, stream>>>(
        (const float4*)z1, gsum, z2gsum, (float4*)out);
}